// Round 20
// baseline (1250.675 us; speedup 1.0000x reference)
//
#include <hip/hip_runtime.h>
#include <hip/hip_bf16.h>
#include <hip/hip_cooperative_groups.h>

namespace cg = cooperative_groups;

#define N_NODES 50000
#define N_EDGES 800000
#define DD 64
#define NBUCKET 782
#define PIDSTRIDE 800
#define NBP (NBUCKET * 8)
#define BN_EPS 1e-5f

// ws layout (fp32 words): bpcnt@0[6400 pid-major], off@6400[50064], boff@56464[800],
//   bpcur@57264[100096], sumsA@157360[128], sumsB[128], tmp32@157632[800000 u32],
//   srt[800000 u16], xb[3.2M bf16].  All zero-init done in-kernel (phase 0).
// d_out (fp32): O1 = h1, O2 = hpre scratch -> h2.

__device__ __forceinline__ float bf2f(unsigned short b) {
    return __uint_as_float(((unsigned)b) << 16);
}
__device__ __forceinline__ float loadF(const void* p, int i, int isf) {
    return isf ? ((const float*)p)[i] : bf2f(((const unsigned short*)p)[i]);
}
template<bool ISF>
__device__ __forceinline__ float4 ld4(const void* p, int i) {
    if (ISF) return *reinterpret_cast<const float4*>((const float*)p + i);
    ushort4 u = *reinterpret_cast<const ushort4*>((const unsigned short*)p + i);
    return make_float4(bf2f(u.x), bf2f(u.y), bf2f(u.z), bf2f(u.w));
}
__device__ __forceinline__ void acc8(float4& a, float4& b, uint4 u) {
    a.x += __uint_as_float(u.x << 16);
    a.y += __uint_as_float(u.x & 0xFFFF0000u);
    a.z += __uint_as_float(u.y << 16);
    a.w += __uint_as_float(u.y & 0xFFFF0000u);
    b.x += __uint_as_float(u.z << 16);
    b.y += __uint_as_float(u.z & 0xFFFF0000u);
    b.z += __uint_as_float(u.w << 16);
    b.w += __uint_as_float(u.w & 0xFFFF0000u);
}

// ---- gather+GEMM+stats for one bucket (R13-frozen lane geometry) ----
__device__ __forceinline__ void gather_phase(
    const unsigned short* __restrict__ xb, const void* __restrict__ self_src, int isf_self,
    const int* __restrict__ off, const unsigned short* __restrict__ srt,
    const void* __restrict__ W, const void* __restrict__ bias, int isfW,
    float* __restrict__ out_, float* __restrict__ sums, int b,
    float (*sIn)[DD], float (*r1)[DD], float (*r2)[DD], int tid)
{
    int lane = tid & 63, w = tid >> 6;
    int rs = lane >> 3, ch = lane & 7;
    int row0 = b * 64;
    int lr = w * 8 + rs;
    int r = row0 + lr;
    float4 a  = make_float4(0.f, 0.f, 0.f, 0.f);
    float4 bb = make_float4(0.f, 0.f, 0.f, 0.f);
    float4 a2 = make_float4(0.f, 0.f, 0.f, 0.f);
    float4 b2 = make_float4(0.f, 0.f, 0.f, 0.f);
    if (r < N_NODES) {
        a  = isf_self ? ld4<true>(self_src, r * DD + 8 * ch)
                      : ld4<false>(self_src, r * DD + 8 * ch);
        bb = isf_self ? ld4<true>(self_src, r * DD + 8 * ch + 4)
                      : ld4<false>(self_src, r * DD + 8 * ch + 4);
        int k0 = off[r], k1 = off[r + 1];
        int k = k0;
        for (; k + 8 <= k1; k += 8) {
            int n0 = srt[k],     n1 = srt[k + 1], n2 = srt[k + 2], n3 = srt[k + 3];
            int n4 = srt[k + 4], n5 = srt[k + 5], n6 = srt[k + 6], n7 = srt[k + 7];
            uint4 u0 = *reinterpret_cast<const uint4*>(xb + n0 * DD + 8 * ch);
            uint4 u1 = *reinterpret_cast<const uint4*>(xb + n1 * DD + 8 * ch);
            uint4 u2 = *reinterpret_cast<const uint4*>(xb + n2 * DD + 8 * ch);
            uint4 u3 = *reinterpret_cast<const uint4*>(xb + n3 * DD + 8 * ch);
            uint4 u4 = *reinterpret_cast<const uint4*>(xb + n4 * DD + 8 * ch);
            uint4 u5 = *reinterpret_cast<const uint4*>(xb + n5 * DD + 8 * ch);
            uint4 u6 = *reinterpret_cast<const uint4*>(xb + n6 * DD + 8 * ch);
            uint4 u7 = *reinterpret_cast<const uint4*>(xb + n7 * DD + 8 * ch);
            acc8(a, bb, u0);
            acc8(a2, b2, u1);
            acc8(a, bb, u2);
            acc8(a2, b2, u3);
            acc8(a, bb, u4);
            acc8(a2, b2, u5);
            acc8(a, bb, u6);
            acc8(a2, b2, u7);
        }
        for (; k + 2 <= k1; k += 2) {
            int n0 = srt[k], n1 = srt[k + 1];
            uint4 u0 = *reinterpret_cast<const uint4*>(xb + n0 * DD + 8 * ch);
            uint4 u1 = *reinterpret_cast<const uint4*>(xb + n1 * DD + 8 * ch);
            acc8(a, bb, u0);
            acc8(a2, b2, u1);
        }
        if (k < k1) {
            int n0 = srt[k];
            acc8(a, bb, *reinterpret_cast<const uint4*>(xb + n0 * DD + 8 * ch));
        }
        a.x += a2.x; a.y += a2.y; a.z += a2.z; a.w += a2.w;
        bb.x += b2.x; bb.y += b2.y; bb.z += b2.z; bb.w += b2.w;
    }
    *reinterpret_cast<float4*>(&sIn[lr][8 * ch]) = a;
    *reinterpret_cast<float4*>(&sIn[lr][8 * ch + 4]) = bb;
    __syncthreads();

    float wcol[DD];
    #pragma unroll
    for (int k = 0; k < DD; ++k) wcol[k] = loadF(W, k * DD + lane, isfW);
    float bv = loadF(bias, lane, isfW);

    float s1 = 0.f, s2 = 0.f;
    #pragma unroll 4
    for (int j = 0; j < 8; ++j) {
        int jr = w * 8 + j;
        float c0 = 0.f, c1 = 0.f, c2 = 0.f, c3 = 0.f;
        #pragma unroll
        for (int k = 0; k < DD; k += 4) {
            float4 aa = *reinterpret_cast<const float4*>(&sIn[jr][k]);
            c0 += aa.x * wcol[k];
            c1 += aa.y * wcol[k + 1];
            c2 += aa.z * wcol[k + 2];
            c3 += aa.w * wcol[k + 3];
        }
        float acc = bv + ((c0 + c1) + (c2 + c3));
        int rr = row0 + jr;
        if (rr < N_NODES) {
            out_[rr * DD + lane] = acc;
            s1 += acc;
            s2 += acc * acc;
        }
    }
    r1[w][lane] = s1; r2[w][lane] = s2;
    __syncthreads();
    if (w == 0) {
        float t1 = 0.f, t2 = 0.f;
        #pragma unroll
        for (int q = 0; q < 8; ++q) { t1 += r1[q][lane]; t2 += r2[q][lane]; }
        atomicAdd(&sums[lane], t1);
        atomicAdd(&sums[64 + lane], t2);
    }
    __syncthreads();
}

// ---- BN+ReLU+GEMM2+ReLU for one bucket (512 threads) ----
__device__ __forceinline__ void mlp2_phase(
    const float* __restrict__ in_, float* __restrict__ sums,
    const void* __restrict__ gma, const void* __restrict__ beta,
    const void* __restrict__ W, const void* __restrict__ bias, int isf,
    float* __restrict__ oF, unsigned short* obf, int b,
    float (*sIn)[DD], float (*r2)[DD], int tid)
{
    int lane = tid & 63, w = tid >> 6;
    int row0 = b * 64;
    if (tid < 64) {
        float S1 = atomicAdd(&sums[tid], 0.0f);        // coherent read (LLC)
        float S2 = atomicAdd(&sums[64 + tid], 0.0f);
        float mean = S1 * (1.0f / N_NODES);
        float var  = S2 * (1.0f / N_NODES) - mean * mean;
        float scale = rsqrtf(var + BN_EPS) * loadF(gma, tid, isf);
        r2[0][tid] = scale;
        r2[1][tid] = loadF(beta, tid, isf) - mean * scale;
    }
    __syncthreads();
    {
        int lr = tid >> 3, cc = (tid & 7) * 8;
        int r = row0 + lr;
        float4 v0 = make_float4(0.f, 0.f, 0.f, 0.f), v1 = v0;
        if (r < N_NODES) {
            v0 = *reinterpret_cast<const float4*>(in_ + r * DD + cc);
            v1 = *reinterpret_cast<const float4*>(in_ + r * DD + cc + 4);
            float4 sc0 = *reinterpret_cast<const float4*>(&r2[0][cc]);
            float4 sc1 = *reinterpret_cast<const float4*>(&r2[0][cc + 4]);
            float4 sh0 = *reinterpret_cast<const float4*>(&r2[1][cc]);
            float4 sh1 = *reinterpret_cast<const float4*>(&r2[1][cc + 4]);
            v0.x = fmaxf(v0.x * sc0.x + sh0.x, 0.f);
            v0.y = fmaxf(v0.y * sc0.y + sh0.y, 0.f);
            v0.z = fmaxf(v0.z * sc0.z + sh0.z, 0.f);
            v0.w = fmaxf(v0.w * sc0.w + sh0.w, 0.f);
            v1.x = fmaxf(v1.x * sc1.x + sh1.x, 0.f);
            v1.y = fmaxf(v1.y * sc1.y + sh1.y, 0.f);
            v1.z = fmaxf(v1.z * sc1.z + sh1.z, 0.f);
            v1.w = fmaxf(v1.w * sc1.w + sh1.w, 0.f);
        }
        *reinterpret_cast<float4*>(&sIn[lr][cc]) = v0;
        *reinterpret_cast<float4*>(&sIn[lr][cc + 4]) = v1;
    }
    __syncthreads();

    float wcol[DD];
    #pragma unroll
    for (int k = 0; k < DD; ++k) wcol[k] = loadF(W, k * DD + lane, isf);
    float bv = loadF(bias, lane, isf);

    #pragma unroll 4
    for (int j = 0; j < 8; ++j) {
        int lr = w * 8 + j;
        float a0 = 0.f, a1 = 0.f, a2 = 0.f, a3 = 0.f;
        #pragma unroll
        for (int k = 0; k < DD; k += 4) {
            float4 aa = *reinterpret_cast<const float4*>(&sIn[lr][k]);
            a0 += aa.x * wcol[k];
            a1 += aa.y * wcol[k + 1];
            a2 += aa.z * wcol[k + 2];
            a3 += aa.w * wcol[k + 3];
        }
        float acc = fmaxf(bv + ((a0 + a1) + (a2 + a3)), 0.f);
        int r = row0 + lr;
        if (r < N_NODES) {
            oF[r * DD + lane] = acc;
            if (obf) obf[r * DD + lane] = __bfloat16_as_ushort(__float2bfloat16(acc));
        }
    }
    __syncthreads();
}

#define GSYNC() do { __threadfence(); grid.sync(); __threadfence(); } while (0)

__global__ __launch_bounds__(512) void fused_kernel(
    const void* x, const int* ei,
    const void* W10, const void* b10, const void* g0, const void* be0,
    const void* W20, const void* b20,
    const void* W11, const void* b11, const void* g1, const void* be1,
    const void* W21, const void* b21,
    int* bpcnt, int* off, int* boff, int* bpcur,
    unsigned int* tmp, unsigned short* srt, unsigned short* xb,
    float* sumsA, float* sumsB, float* O1, float* O2)
{
    cg::grid_group grid = cg::this_grid();
    __shared__ float sIn[64][DD];             // 16 KB (aliases: scan tmp, etc.)
    __shared__ float r1[8][DD], r2[8][DD];    // 4 KB  (aliases: fillB counters)
    __shared__ int cntF, cntI;
    int tid = threadIdx.x;
    int bid = blockIdx.x;
    int nb  = gridDim.x;
    int gstride = nb * 512;

    // local sniff (deterministic, every block)
    if (tid == 0) { cntF = 0; cntI = 0; }
    __syncthreads();
    if (tid < 256) {
        unsigned short wd = ((const unsigned short*)x)[2 * tid];
        int e = (wd >> 7) & 0xFF;
        if (e >= 0x70 && e <= 0x8F) atomicAdd(&cntF, 1);
    }
    if (tid < 128 && ei[2 * tid + 1] == 0) atomicAdd(&cntI, 1);
    __syncthreads();
    int isf = (cntF < 128) ? 1 : 0;
    int i64 = (cntI > 64) ? 1 : 0;

    // P0: zero bpcnt + sums; cast x -> bf16 xb
    for (int i = bid * 512 + tid; i < 8 * PIDSTRIDE; i += gstride) bpcnt[i] = 0;
    if (bid == 0 && tid < 128) { sumsA[tid] = 0.0f; sumsB[tid] = 0.0f; }
    for (int g = bid * 512 + tid; g < N_NODES * DD / 8; g += gstride) {
        int i = g * 8;
        if (isf) {
            float4 a = *reinterpret_cast<const float4*>((const float*)x + i);
            float4 b = *reinterpret_cast<const float4*>((const float*)x + i + 4);
            ushort4 o0, o1;
            o0.x = __bfloat16_as_ushort(__float2bfloat16(a.x));
            o0.y = __bfloat16_as_ushort(__float2bfloat16(a.y));
            o0.z = __bfloat16_as_ushort(__float2bfloat16(a.z));
            o0.w = __bfloat16_as_ushort(__float2bfloat16(a.w));
            o1.x = __bfloat16_as_ushort(__float2bfloat16(b.x));
            o1.y = __bfloat16_as_ushort(__float2bfloat16(b.y));
            o1.z = __bfloat16_as_ushort(__float2bfloat16(b.z));
            o1.w = __bfloat16_as_ushort(__float2bfloat16(b.w));
            *reinterpret_cast<ushort4*>(xb + i) = o0;
            *reinterpret_cast<ushort4*>(xb + i + 4) = o1;
        } else {
            *reinterpret_cast<uint4*>(xb + i) =
                *reinterpret_cast<const uint4*>((const unsigned short*)x + i);
        }
    }
    GSYNC();

    // P1: pid-major bucket histogram
    for (int e = bid * 512 + tid; e < N_EDGES; e += gstride) {
        int d = i64 ? ei[2 * N_EDGES + 2 * e] : ei[N_EDGES + e];
        atomicAdd(bpcnt + (bid & 7) * PIDSTRIDE + (d >> 6), 1);
    }
    GSYNC();

    // P2: block-0 scan over (bucket-major, pid-minor) -> bpcur, boff
    if (bid == 0) {
        int* iTmp = (int*)&sIn[0][0];
        const int CH = 13;                    // 512*13 >= 6256
        int lo = tid * CH, hi = lo + CH; if (hi > NBP) hi = NBP;
        int s = 0;
        for (int i = lo; i < hi; ++i)
            s += atomicAdd(&bpcnt[(i & 7) * PIDSTRIDE + (i >> 3)], 0);
        iTmp[tid] = s;
        __syncthreads();
        for (int d = 1; d < 512; d <<= 1) {
            int u = (tid >= d) ? iTmp[tid - d] : 0;
            __syncthreads();
            iTmp[tid] += u;
            __syncthreads();
        }
        int run = (tid == 0) ? 0 : iTmp[tid - 1];
        for (int i = lo; i < hi; ++i) {
            int c = atomicAdd(&bpcnt[(i & 7) * PIDSTRIDE + (i >> 3)], 0);
            bpcur[i * 16] = run;
            if ((i & 7) == 0) boff[i >> 3] = run;
            run += c;
        }
        if (tid == 511) boff[NBUCKET] = iTmp[511];
    }
    GSYNC();

    // P3: fillA — scatter edges into (bucket, bid&7) sub-spans
    for (int e = bid * 512 + tid; e < N_EDGES; e += gstride) {
        int s, d;
        if (i64) { s = ei[2 * e]; d = ei[2 * N_EDGES + 2 * e]; }
        else     { s = ei[e];     d = ei[N_EDGES + e]; }
        int bin = (d >> 6) * 8 + (bid & 7);
        int pos = atomicAdd(bpcur + bin * 16, 1);
        tmp[pos] = (unsigned)s | ((unsigned)(d & 63) << 16);
    }
    GSYNC();

    // P4: fillB — per-node off[] + srt placement (one bucket per block iteration)
    for (int b = bid; b < NBUCKET; b += nb) {
        int* lcnt = (int*)&r1[0][0];
        int* cur  = lcnt + 64;
        if (tid < 64) lcnt[tid] = 0;
        __syncthreads();
        int start = boff[b], end = boff[b + 1];
        for (int i = start + tid; i < end; i += 512)
            atomicAdd(&lcnt[tmp[i] >> 16], 1);
        __syncthreads();
        if (tid < 64) {
            int v = lcnt[tid];
            int s = v;
            #pragma unroll
            for (int d = 1; d < 64; d <<= 1) {
                int u = __shfl_up(s, d, 64);
                if (tid >= d) s += u;
            }
            int o = start + (s - v);
            int node = b * 64 + tid;
            if (node <= N_NODES) off[node] = o;
            cur[tid] = o;
        }
        __syncthreads();
        for (int i = start + tid; i < end; i += 512) {
            unsigned v = tmp[i];
            int pos = atomicAdd(&cur[v >> 16], 1);
            srt[pos] = (unsigned short)(v & 0xFFFFu);
        }
        __syncthreads();
    }
    GSYNC();

    // P5: layer-1 gather+GEMM1+stats
    for (int b = bid; b < NBUCKET; b += nb)
        gather_phase(xb, x, isf, off, srt, W10, b10, isf, O2, sumsA, b, sIn, r1, r2, tid);
    GSYNC();

    // P6: layer-1 BN+ReLU+GEMM2+ReLU -> O1 (+ bf16 shadow into xb)
    for (int b = bid; b < NBUCKET; b += nb)
        mlp2_phase(O2, sumsA, g0, be0, W20, b20, isf, O1, xb, b, sIn, r2, tid);
    GSYNC();

    // P7: layer-2 gather+GEMM1+stats (self term = fp32 h1 in O1)
    for (int b = bid; b < NBUCKET; b += nb)
        gather_phase(xb, O1, 1, off, srt, W11, b11, isf, O2, sumsB, b, sIn, r1, r2, tid);
    GSYNC();

    // P8: layer-2 BN+ReLU+GEMM2+ReLU -> O2 (in-place, block-local staging)
    for (int b = bid; b < NBUCKET; b += nb)
        mlp2_phase(O2, sumsB, g1, be1, W21, b21, isf, O2, nullptr, b, sIn, r2, tid);
}

extern "C" void kernel_launch(void* const* d_in, const int* in_sizes, int n_in,
                              void* d_out, int out_size, void* d_ws, size_t ws_size,
                              hipStream_t stream)
{
    (void)in_sizes; (void)n_in; (void)out_size; (void)ws_size;
    const void* x  = d_in[0];
    const int* ei  = (const int*)d_in[1];
    const void* W1_0 = d_in[2];  const void* b1_0 = d_in[3];
    const void* g_0  = d_in[4];  const void* be_0 = d_in[5];
    const void* W2_0 = d_in[6];  const void* b2_0 = d_in[7];
    const void* W1_1 = d_in[8];  const void* b1_1 = d_in[9];
    const void* g_1  = d_in[10]; const void* be_1 = d_in[11];
    const void* W2_1 = d_in[12]; const void* b2_1 = d_in[13];

    int*  bpcnt  = (int*)d_ws;                     // 6400 pid-major
    int*  off    = bpcnt + 6400;                   // 50064
    int*  boff   = off + 50064;                    // 800
    int*  bpcur  = boff + 800;                     // 100096 (line-padded)
    float* sumsA = (float*)(bpcur + 100096);       // 128
    float* sumsB = sumsA + 128;                    // 128
    unsigned int* tmp32 = (unsigned int*)(sumsB + 128) + 16;  // 800000, 16B-aligned
    unsigned short* srt = (unsigned short*)(tmp32 + 800000);  // 800000 u16
    unsigned short* xb  = srt + 800064;                       // 3.2M bf16
    float* O1 = (float*)d_out;
    float* O2 = O1 + (size_t)N_NODES * DD;

    int maxB = 0;
    hipOccupancyMaxActiveBlocksPerMultiprocessor(&maxB, (const void*)fused_kernel, 512, 0);
    if (maxB < 1) maxB = 1;
    int grid = maxB * 256;                         // 256 CUs on MI355X
    if (grid > NBUCKET) grid = NBUCKET;

    void* kx = (void*)x;       void* kei = (void*)ei;
    void* a0 = (void*)W1_0;    void* a1 = (void*)b1_0;
    void* a2 = (void*)g_0;     void* a3 = (void*)be_0;
    void* a4 = (void*)W2_0;    void* a5 = (void*)b2_0;
    void* a6 = (void*)W1_1;    void* a7 = (void*)b1_1;
    void* a8 = (void*)g_1;     void* a9 = (void*)be_1;
    void* a10 = (void*)W2_1;   void* a11 = (void*)b2_1;
    void* args[] = {
        &kx, &kei, &a0, &a1, &a2, &a3, &a4, &a5, &a6, &a7, &a8, &a9, &a10, &a11,
        &bpcnt, &off, &boff, &bpcur, &tmp32, &srt, &xb, &sumsA, &sumsB, &O1, &O2
    };
    hipLaunchCooperativeKernel((const void*)fused_kernel, dim3(grid), dim3(512),
                               args, 0, stream);
}

// Round 21
// 304.029 us; speedup vs baseline: 4.1137x; 4.1137x over previous
//
#include <hip/hip_runtime.h>
#include <hip/hip_bf16.h>

#define N_NODES 50000
#define N_EDGES 800000
#define DD 64
#define RPB 64
#define GBLOCKS ((N_NODES + RPB - 1) / RPB)       // 782
#define MBLOCKS ((N_NODES + 63) / 64)             // 782
#define NBUCKET ((N_NODES + 63) / 64)             // 782
#define SCAN_BLOCKS ((N_NODES + 255) / 256)       // 196
#define EDGE_BLOCKS (N_EDGES / 256)               // 3125
#define BN_EPS 1e-5f

// R16 configuration — measured best (305.4 us). ws layout (fp32 words), ~11.7 MB:
//   [0..127] sumsA  [128..255] sumsB  [256..] flags (isf, i64)
//   cnt@512[50048], off[50064], bcur[782*16 line-padded], bsum[256],
//   tmp32[800000 u32], srt[800000 u16], xb[3.2M bf16]
// Words [0 .. 50560) zeroed by hipMemsetAsync before initcast (sums + flags + cnt).
// d_out (fp32): O1 = h1 (fp32 self-term source), O2 = hpre scratch -> h2.

__device__ __forceinline__ float bf2f(unsigned short b) {
    return __uint_as_float(((unsigned)b) << 16);
}
__device__ __forceinline__ float loadF(const void* p, int i, int isf) {
    return isf ? ((const float*)p)[i] : bf2f(((const unsigned short*)p)[i]);
}
template<bool ISF>
__device__ __forceinline__ float4 ld4(const void* p, int i) {
    if (ISF) return *reinterpret_cast<const float4*>((const float*)p + i);
    ushort4 u = *reinterpret_cast<const ushort4*>((const unsigned short*)p + i);
    return make_float4(bf2f(u.x), bf2f(u.y), bf2f(u.z), bf2f(u.w));
}
// accumulate 8 bf16 (packed in uint4) into two float4s
__device__ __forceinline__ void acc8(float4& a, float4& b, uint4 u) {
    a.x += __uint_as_float(u.x << 16);
    a.y += __uint_as_float(u.x & 0xFFFF0000u);
    a.z += __uint_as_float(u.y << 16);
    a.w += __uint_as_float(u.y & 0xFFFF0000u);
    b.x += __uint_as_float(u.z << 16);
    b.y += __uint_as_float(u.z & 0xFFFF0000u);
    b.z += __uint_as_float(u.w << 16);
    b.w += __uint_as_float(u.w & 0xFFFF0000u);
}

// Merged: sniff (local per block), node-histogram (1 edge/thread), cast x -> bf16 xb.
// cnt/sums pre-zeroed by hipMemsetAsync. Grid = 3125 (one thread per edge).
__global__ __launch_bounds__(256) void initcast_kernel(
    const void* __restrict__ x, const int* __restrict__ ei,
    int* __restrict__ flags, int* __restrict__ cnt,
    unsigned short* __restrict__ xb)
{
    __shared__ int cntF, cntI;
    int t = threadIdx.x;
    if (t == 0) { cntF = 0; cntI = 0; }
    __syncthreads();
    unsigned short wd = ((const unsigned short*)x)[2 * t];
    int e = (wd >> 7) & 0xFF;
    if (e >= 0x70 && e <= 0x8F) atomicAdd(&cntF, 1);        // bf16-plausible exponent
    if (t < 128 && ei[2 * t + 1] == 0) atomicAdd(&cntI, 1); // int64 high words are 0
    __syncthreads();
    int isf = (cntF < 128) ? 1 : 0;
    int i64 = (cntI > 64) ? 1 : 0;

    int gid = blockIdx.x * 256 + t;
    if (blockIdx.x == 0 && t == 0) {
        flags[0] = isf;
        flags[1] = i64;
    }

    // histogram: this thread's edge
    {
        int d = i64 ? ei[2 * N_EDGES + 2 * gid] : ei[N_EDGES + gid];
        atomicAdd(cnt + d, 1);
    }

    // cast: 8 elems/thread for gid < 400000
    int i = gid * 8;
    if (i < N_NODES * DD) {
        if (isf) {
            float4 a = *reinterpret_cast<const float4*>((const float*)x + i);
            float4 b = *reinterpret_cast<const float4*>((const float*)x + i + 4);
            ushort4 o0, o1;
            o0.x = __bfloat16_as_ushort(__float2bfloat16(a.x));
            o0.y = __bfloat16_as_ushort(__float2bfloat16(a.y));
            o0.z = __bfloat16_as_ushort(__float2bfloat16(a.z));
            o0.w = __bfloat16_as_ushort(__float2bfloat16(a.w));
            o1.x = __bfloat16_as_ushort(__float2bfloat16(b.x));
            o1.y = __bfloat16_as_ushort(__float2bfloat16(b.y));
            o1.z = __bfloat16_as_ushort(__float2bfloat16(b.z));
            o1.w = __bfloat16_as_ushort(__float2bfloat16(b.w));
            *reinterpret_cast<ushort4*>(xb + i) = o0;
            *reinterpret_cast<ushort4*>(xb + i + 4) = o1;
        } else {
            *reinterpret_cast<uint4*>(xb + i) =
                *reinterpret_cast<const uint4*>((const unsigned short*)x + i);
        }
    }
}

// block-local exclusive scan into off + per-block sums
__global__ __launch_bounds__(256) void scanA_kernel(const int* __restrict__ cnt,
                                                    int* __restrict__ off,
                                                    int* __restrict__ bsum) {
    __shared__ int tmp[256];
    int t = threadIdx.x;
    int i = blockIdx.x * 256 + t;
    int v = (i < N_NODES) ? cnt[i] : 0;
    tmp[t] = v;
    __syncthreads();
    #pragma unroll
    for (int d = 1; d < 256; d <<= 1) {
        int u = (t >= d) ? tmp[t - d] : 0;
        __syncthreads();
        tmp[t] += u;
        __syncthreads();
    }
    if (i < N_NODES) off[i] = tmp[t] - v;
    if (t == 255) bsum[blockIdx.x] = tmp[255];
}

// scanB folded in: every block redundantly scans bsum[196] in LDS, then adds its base.
// Also seeds bucket cursors (bcur, line-padded stride 16) and off[N_NODES].
__global__ __launch_bounds__(256) void scanC_kernel(const int* __restrict__ bsum,
                                                    int* __restrict__ off,
                                                    int* __restrict__ bcur) {
    __shared__ int tmp[256];
    int t = threadIdx.x;
    int v = (t < SCAN_BLOCKS) ? bsum[t] : 0;
    tmp[t] = v;
    __syncthreads();
    #pragma unroll
    for (int d = 1; d < 256; d <<= 1) {
        int u = (t >= d) ? tmp[t - d] : 0;
        __syncthreads();
        tmp[t] += u;
        __syncthreads();
    }
    int base = (blockIdx.x == 0) ? 0 : tmp[blockIdx.x - 1];
    int i = blockIdx.x * 256 + t;
    if (i < N_NODES) {
        int o = off[i] + base;
        off[i] = o;
        if ((i & 63) == 0) bcur[(i >> 6) * 16] = o;
    }
    if (blockIdx.x == SCAN_BLOCKS - 1 && t == 0) off[N_NODES] = tmp[SCAN_BLOCKS - 1];
}

// Pass A: scatter edges into their bucket's contiguous span (bucket = dst>>6).
__global__ void fillA_kernel(const int* __restrict__ ei, int* __restrict__ bcur,
                             unsigned int* __restrict__ tmp, const int* __restrict__ flags) {
    int i64 = flags[1];
    int e = blockIdx.x * 256 + threadIdx.x;
    int s, d;
    if (i64) { s = ei[2 * e]; d = ei[2 * N_EDGES + 2 * e]; }
    else     { s = ei[e];     d = ei[N_EDGES + e]; }
    int b = d >> 6;
    int pos = atomicAdd(bcur + b * 16, 1);
    tmp[pos] = (unsigned)s | ((unsigned)(d & 63) << 16);
}

// Pass B: one block per bucket; exact per-node placement via LDS counters.
__global__ __launch_bounds__(256) void fillB_kernel(const int* __restrict__ off,
                                                    const unsigned int* __restrict__ tmp,
                                                    unsigned short* __restrict__ srt) {
    __shared__ int cur64[64];
    int b = blockIdx.x;
    int t = threadIdx.x;
    if (t < 64) {
        int idx = b * 64 + t;
        cur64[t] = (idx < N_NODES) ? off[idx] : N_EDGES;
    }
    __syncthreads();
    int start = off[b * 64];
    int endn  = (b + 1) * 64; if (endn > N_NODES) endn = N_NODES;
    int end   = off[endn];
    for (int i = start + t; i < end; i += 256) {
        unsigned v = tmp[i];
        int pos = atomicAdd(&cur64[v >> 16], 1);
        srt[pos] = (unsigned short)(v & 0xFFFFu);
    }
}

// Fused: CSR bf16-gather -> LDS -> GEMM (W1,b1) -> hpre + BN sums.
// R13-proven local optimum: 512 threads = 8 waves x 8 row-slots; lane (rs = lane>>3,
// ch = lane&7) owns the FULL neighbor stream of row (w*8+rs), chunk ch; per-element
// u16 srt reads; 8-deep load pipeline per lane. DO NOT alter lane geometry
// (R10/R12/R14/R15 all regressed; cooperative fusion R20 regressed 4x).
__global__ __launch_bounds__(512) void gather_gemm_stats_kernel(
    const unsigned short* __restrict__ xb, const void* __restrict__ self_src, int force_f32,
    const int* __restrict__ off, const unsigned short* __restrict__ srt,
    const void* __restrict__ W, const void* __restrict__ bias,
    float* __restrict__ out_, float* __restrict__ sums, const int* __restrict__ flags)
{
    __shared__ float sIn[RPB][DD];            // 16 KB agg tile
    __shared__ float r1[8][DD], r2[8][DD];    // 4 KB stats
    int tid = threadIdx.x;
    int lane = tid & 63, w = tid >> 6;        // wave 0..7
    int rs = lane >> 3, ch = lane & 7;
    int row0 = blockIdx.x * RPB;
    int isf = force_f32 ? 1 : flags[0];

    int lr = w * 8 + rs;
    int r = row0 + lr;
    float4 a  = make_float4(0.f, 0.f, 0.f, 0.f);
    float4 b  = make_float4(0.f, 0.f, 0.f, 0.f);
    float4 a2 = make_float4(0.f, 0.f, 0.f, 0.f);
    float4 b2 = make_float4(0.f, 0.f, 0.f, 0.f);
    if (r < N_NODES) {
        a = isf ? ld4<true>(self_src, r * DD + 8 * ch)
                : ld4<false>(self_src, r * DD + 8 * ch);
        b = isf ? ld4<true>(self_src, r * DD + 8 * ch + 4)
                : ld4<false>(self_src, r * DD + 8 * ch + 4);
        int k0 = off[r], k1 = off[r + 1];
        int k = k0;
        for (; k + 8 <= k1; k += 8) {         // 8-deep pipelined neighbor loads
            int n0 = srt[k],     n1 = srt[k + 1], n2 = srt[k + 2], n3 = srt[k + 3];
            int n4 = srt[k + 4], n5 = srt[k + 5], n6 = srt[k + 6], n7 = srt[k + 7];
            uint4 u0 = *reinterpret_cast<const uint4*>(xb + n0 * DD + 8 * ch);
            uint4 u1 = *reinterpret_cast<const uint4*>(xb + n1 * DD + 8 * ch);
            uint4 u2 = *reinterpret_cast<const uint4*>(xb + n2 * DD + 8 * ch);
            uint4 u3 = *reinterpret_cast<const uint4*>(xb + n3 * DD + 8 * ch);
            uint4 u4 = *reinterpret_cast<const uint4*>(xb + n4 * DD + 8 * ch);
            uint4 u5 = *reinterpret_cast<const uint4*>(xb + n5 * DD + 8 * ch);
            uint4 u6 = *reinterpret_cast<const uint4*>(xb + n6 * DD + 8 * ch);
            uint4 u7 = *reinterpret_cast<const uint4*>(xb + n7 * DD + 8 * ch);
            acc8(a, b, u0);
            acc8(a2, b2, u1);
            acc8(a, b, u2);
            acc8(a2, b2, u3);
            acc8(a, b, u4);
            acc8(a2, b2, u5);
            acc8(a, b, u6);
            acc8(a2, b2, u7);
        }
        for (; k + 2 <= k1; k += 2) {
            int n0 = srt[k], n1 = srt[k + 1];
            uint4 u0 = *reinterpret_cast<const uint4*>(xb + n0 * DD + 8 * ch);
            uint4 u1 = *reinterpret_cast<const uint4*>(xb + n1 * DD + 8 * ch);
            acc8(a, b, u0);
            acc8(a2, b2, u1);
        }
        if (k < k1) {
            int n0 = srt[k];
            acc8(a, b, *reinterpret_cast<const uint4*>(xb + n0 * DD + 8 * ch));
        }
        a.x += a2.x; a.y += a2.y; a.z += a2.z; a.w += a2.w;
        b.x += b2.x; b.y += b2.y; b.z += b2.z; b.w += b2.w;
    }
    *reinterpret_cast<float4*>(&sIn[lr][8 * ch]) = a;
    *reinterpret_cast<float4*>(&sIn[lr][8 * ch + 4]) = b;
    __syncthreads();

    float wcol[DD];                           // W[:,c], c = lane
    #pragma unroll
    for (int k = 0; k < DD; ++k) wcol[k] = loadF(W, k * DD + lane, isf);
    float bv = loadF(bias, lane, isf);

    float s1 = 0.f, s2 = 0.f;
    #pragma unroll 4
    for (int j = 0; j < 8; ++j) {
        int jr = w * 8 + j;
        float c0 = 0.f, c1 = 0.f, c2 = 0.f, c3 = 0.f;
        #pragma unroll
        for (int k = 0; k < DD; k += 4) {
            float4 aa = *reinterpret_cast<const float4*>(&sIn[jr][k]);  // wave-uniform broadcast
            c0 += aa.x * wcol[k];
            c1 += aa.y * wcol[k + 1];
            c2 += aa.z * wcol[k + 2];
            c3 += aa.w * wcol[k + 3];
        }
        float acc = bv + ((c0 + c1) + (c2 + c3));
        int rr = row0 + jr;
        if (rr < N_NODES) {
            out_[rr * DD + lane] = acc;
            s1 += acc;
            s2 += acc * acc;
        }
    }
    r1[w][lane] = s1; r2[w][lane] = s2;
    __syncthreads();
    if (w == 0) {
        float t1 = 0.f, t2 = 0.f;
        #pragma unroll
        for (int q = 0; q < 8; ++q) { t1 += r1[q][lane]; t2 += r2[q][lane]; }
        atomicAdd(&sums[lane], t1);
        atomicAdd(&sums[64 + lane], t2);
    }
}

// h = relu(hpre*scale+shift); out = relu(h @ W2 + b2) -> fp32 (+ optional bf16 shadow).
// BN scale/shift computed inline from sums. In-place safe (LDS staged).
__global__ __launch_bounds__(256) void mlp2_kernel(
    const float* __restrict__ in_, const float* __restrict__ sums,
    const void* __restrict__ gma, const void* __restrict__ beta,
    const void* __restrict__ W, const void* __restrict__ bias,
    float* __restrict__ oF, unsigned short* obf, const int* __restrict__ flags)
{
    __shared__ float sIn[64][DD];
    __shared__ float sScale[DD], sShift[DD];
    int isf = flags[0];
    int tid = threadIdx.x;
    int c = tid & 63, g = tid >> 6;
    int row0 = blockIdx.x * 64;

    if (tid < 64) {
        float S1 = sums[tid];
        float S2 = sums[64 + tid];
        float mean = S1 * (1.0f / N_NODES);
        float var  = S2 * (1.0f / N_NODES) - mean * mean;
        float scale = rsqrtf(var + BN_EPS) * loadF(gma, tid, isf);
        sScale[tid] = scale;
        sShift[tid] = loadF(beta, tid, isf) - mean * scale;
    }
    __syncthreads();

    #pragma unroll
    for (int j = 0; j < 4; ++j) {
        int lr = (tid >> 4) + 16 * j;
        int cc = (tid & 15) << 2;
        int r = row0 + lr;
        float4 v = make_float4(0.f, 0.f, 0.f, 0.f);
        if (r < N_NODES) {
            v = *reinterpret_cast<const float4*>(in_ + r * DD + cc);
            float4 sc = *reinterpret_cast<const float4*>(&sScale[cc]);
            float4 sh = *reinterpret_cast<const float4*>(&sShift[cc]);
            v.x = fmaxf(v.x * sc.x + sh.x, 0.f);
            v.y = fmaxf(v.y * sc.y + sh.y, 0.f);
            v.z = fmaxf(v.z * sc.z + sh.z, 0.f);
            v.w = fmaxf(v.w * sc.w + sh.w, 0.f);
        }
        *reinterpret_cast<float4*>(&sIn[lr][cc]) = v;
    }
    __syncthreads();

    float wcol[DD];
    #pragma unroll
    for (int k = 0; k < DD; ++k) wcol[k] = loadF(W, k * DD + c, isf);
    float bv = loadF(bias, c, isf);

    #pragma unroll 4
    for (int j = 0; j < 16; ++j) {
        int lr = g * 16 + j;
        float a0 = 0.f, a1 = 0.f, a2 = 0.f, a3 = 0.f;
        #pragma unroll
        for (int k = 0; k < DD; k += 4) {
            float4 a = *reinterpret_cast<const float4*>(&sIn[lr][k]);
            a0 += a.x * wcol[k];
            a1 += a.y * wcol[k + 1];
            a2 += a.z * wcol[k + 2];
            a3 += a.w * wcol[k + 3];
        }
        float acc = fmaxf(bv + ((a0 + a1) + (a2 + a3)), 0.f);
        int r = row0 + lr;
        if (r < N_NODES) {
            oF[r * DD + c] = acc;
            if (obf) obf[r * DD + c] = __bfloat16_as_ushort(__float2bfloat16(acc));
        }
    }
}

extern "C" void kernel_launch(void* const* d_in, const int* in_sizes, int n_in,
                              void* d_out, int out_size, void* d_ws, size_t ws_size,
                              hipStream_t stream)
{
    (void)in_sizes; (void)n_in; (void)out_size; (void)ws_size;
    const void* x  = d_in[0];
    const int* ei  = (const int*)d_in[1];
    const void* W1_0 = d_in[2];  const void* b1_0 = d_in[3];
    const void* g_0  = d_in[4];  const void* be_0 = d_in[5];
    const void* W2_0 = d_in[6];  const void* b2_0 = d_in[7];
    const void* W1_1 = d_in[8];  const void* b1_1 = d_in[9];
    const void* g_1  = d_in[10]; const void* be_1 = d_in[11];
    const void* W2_1 = d_in[12]; const void* b2_1 = d_in[13];

    float* wsf   = (float*)d_ws;
    float* sumsA = wsf;                            // 128
    float* sumsB = wsf + 128;                      // 128
    int*  flags  = (int*)(wsf + 256);              // 2
    int*  cnt    = (int*)(wsf + 512);              // 50048
    int*  off    = cnt + 50048;                    // 50064
    int*  bcur   = off + 50064;                    // 782*16 = 12512 (line-padded)
    int*  bsum   = bcur + 12512;                   // 256
    unsigned int* tmp32 = (unsigned int*)(bsum + 256) + 48;   // 800000 u32
    unsigned short* srt = (unsigned short*)(tmp32 + 800000);  // 800000 u16
    unsigned short* xb  = srt + 800064;                       // 3.2M bf16, 16B-aligned
    float* O1    = (float*)d_out;                  // h1 (fp32 self-term source)
    float* O2    = O1 + (size_t)N_NODES * DD;      // hpre scratch -> h2

    dim3 blk(256);

    // zero sums/flags/cnt, then CSR build (hist folded into initcast) + bf16 shadow
    hipMemsetAsync(d_ws, 0, (size_t)(512 + 50048) * 4, stream);
    initcast_kernel<<<EDGE_BLOCKS, blk, 0, stream>>>(x, ei, flags, cnt, xb);
    scanA_kernel<<<SCAN_BLOCKS, blk, 0, stream>>>(cnt, off, bsum);
    scanC_kernel<<<SCAN_BLOCKS, blk, 0, stream>>>(bsum, off, bcur);
    fillA_kernel<<<EDGE_BLOCKS, blk, 0, stream>>>(ei, bcur, tmp32, flags);
    fillB_kernel<<<NBUCKET, blk, 0, stream>>>(off, tmp32, srt);

    // ---- layer 1 ----
    gather_gemm_stats_kernel<<<GBLOCKS, 512, 0, stream>>>(xb, x, 0, off, srt, W1_0, b1_0,
                                                          O2, sumsA, flags);
    mlp2_kernel<<<MBLOCKS, blk, 0, stream>>>(O2, sumsA, g_0, be_0, W2_0, b2_0, O1, xb, flags);

    // ---- layer 2 ----
    gather_gemm_stats_kernel<<<GBLOCKS, 512, 0, stream>>>(xb, O1, 1, off, srt, W1_1, b1_1,
                                                          O2, sumsB, flags);
    mlp2_kernel<<<MBLOCKS, blk, 0, stream>>>(O2, sumsB, g_1, be_1, W2_1, b2_1, O2, nullptr, flags);
}